// Round 9
// baseline (9674.888 us; speedup 1.0000x reference)
//
#include <hip/hip_runtime.h>

#define Bn 64
#define Tn 1024
#define Cn 256
#define NBF (Bn / 2)  // 32 fwd blocks, 2 independent batches per block
#define TCROWS 127  // transT rows cached in bwd LDS (127KB + 32KB ring + tags < 160KB)

// Native clang vector for nontemporal builtins (HIP float4 is a class type).
typedef float nv4 __attribute__((ext_vector_type(4)));
__device__ __forceinline__ float4 nt_load4(const float* p) {
  nv4 r = __builtin_nontemporal_load((const nv4*)p);
  return make_float4(r.x, r.y, r.z, r.w);
}
__device__ __forceinline__ void nt_store4(float* p, float4 v) {
  nv4 r = {v.x, v.y, v.z, v.w};
  __builtin_nontemporal_store(r, (nv4*)p);
}

// R12: barrier that waits ONLY on LDS (lgkmcnt), leaving lane-private global
// stores/loads in flight across the barrier (no cross-wave ordering needed).
#define BAR_LGKM() asm volatile("s_waitcnt lgkmcnt(0)\n\ts_barrier" ::: "memory")

// ---------------- DPP helpers ----------------
template<int CTRL>
__device__ __forceinline__ float dpp_mov_f(float x) {
  return __int_as_float(__builtin_amdgcn_update_dpp(0, __float_as_int(x), CTRL, 0xF, 0xF, true));
}

// R16 (verified -30us): packed (value,index) DPP argmax — no SALU round trips
// inside the backtrack chain. Tie-break = jnp.argmax (min index): in-lane
// strict '>' keeps earliest; cross-lane 'pv >= mv' lets the LOWER lane win
// (lane order == class order; shr1/2/4/8 prefix + bcast15 + bcast31 covers
// all 64 lanes — lane 63 holds the global winner). Untargeted lanes receive
// old = -inf, which never beats finite data.
template<int CTRL>
__device__ __forceinline__ void am_stage(float& mv, int& mi) {
  const float pv = __int_as_float(__builtin_amdgcn_update_dpp(
      (int)0xFF800000, __float_as_int(mv), CTRL, 0xF, 0xF, false));
  const int pi = __builtin_amdgcn_update_dpp(0, mi, CTRL, 0xF, 0xF, false);
  const bool take = (pv >= mv);
  mv = take ? pv : mv;
  mi = take ? pi : mi;
}
__device__ __forceinline__ int argmax64_fast(float v, int i) {
  float mv = v;
  int mi = i;
  am_stage<0x111>(mv, mi);  // row_shr:1
  am_stage<0x112>(mv, mi);  // row_shr:2
  am_stage<0x114>(mv, mi);  // row_shr:4
  am_stage<0x118>(mv, mi);  // row_shr:8
  am_stage<0x142>(mv, mi);  // row_bcast15
  am_stage<0x143>(mv, mi);  // row_bcast31 -> lane 63 has global argmax
  return __builtin_amdgcn_readlane(mi, 63);
}

// Padded alpha LDS layout (R3-verified: conflicts 5.0e7 -> 512):
// 4-float chunk m at float offset (m>>2)*20 + (m&3)*4. Buffer = 320 floats.
__device__ __forceinline__ int apad(int m) { return (m >> 2) * 20 + (m & 3) * 4; }

// Reduce 16 cp cells into accumulator M for one cc component CMP of trans
// fragment TT (correctness-verified in R15). Compiler fuses to v_max3; exact.
#define REDUCE_CC(M, TT, CMP)                                                 \
  {                                                                           \
    M = fmaxf(A0.x + TT[0].CMP, A0.y + TT[1].CMP);                            \
    M = fmaxf(M, A0.z + TT[2].CMP); M = fmaxf(M, A0.w + TT[3].CMP);           \
    M = fmaxf(M, A1.x + TT[4].CMP); M = fmaxf(M, A1.y + TT[5].CMP);           \
    M = fmaxf(M, A1.z + TT[6].CMP); M = fmaxf(M, A1.w + TT[7].CMP);           \
    M = fmaxf(M, A2.x + TT[8].CMP); M = fmaxf(M, A2.y + TT[9].CMP);           \
    M = fmaxf(M, A2.z + TT[10].CMP); M = fmaxf(M, A2.w + TT[11].CMP);         \
    M = fmaxf(M, A3.x + TT[12].CMP); M = fmaxf(M, A3.y + TT[13].CMP);         \
    M = fmaxf(M, A3.z + TT[14].CMP); M = fmaxf(M, A3.w + TT[15].CMP);         \
  }

// One DPP rotate-reduce stage over 8 accumulators (16 c-lanes, exact).
#define DPP_STAGE8(CT)                                                        \
  m0 = fmaxf(m0, dpp_mov_f<CT>(m0)); m1 = fmaxf(m1, dpp_mov_f<CT>(m1));      \
  m2 = fmaxf(m2, dpp_mov_f<CT>(m2)); m3 = fmaxf(m3, dpp_mov_f<CT>(m3));      \
  m4 = fmaxf(m4, dpp_mov_f<CT>(m4)); m5 = fmaxf(m5, dpp_mov_f<CT>(m5));      \
  m6 = fmaxf(m6, dpp_mov_f<CT>(m6)); m7 = fmaxf(m7, dpp_mov_f<CT>(m7));

// ---------------- Kernel A: forward max-plus scan (+ trans transpose) ----------------
// R19: TWO independent batches per 1024-thread block. Rationale: fwd step =
// 2160cy wall vs ~1200cy per-SIMD issue — ~45% of issue slots are empty, and
// every intra-batch scheduling fix failed (R13/14/15/17). This fills the
// slots with INDEPENDENT work: threads 0-511 run batch 2bx (R15 8-wave
// layout, correctness-verified), threads 512-1023 run batch 2bx+1. Each SIMD
// holds 2+2 waves of the two batches at the same 4-wave/SIMD occupancy; DS
// traffic per CU per step unchanged (16 waves x 4 b128), halved per batch.
// Evades R15's failure (2 waves/SIMD) and R13's (added serial sync — here
// the groups merely share the existing barrier with identical work).
__global__ __launch_bounds__(1024, 4) void crf_fwd_kernel(
    float* __restrict__ seq, const float* __restrict__ trans,
    float* __restrict__ transT, int useT) {
  __shared__ float lds[64 * 65];
  __shared__ float ab[2][2][320];  // [batch-group][parity][padded alpha]
  const int bx = blockIdx.x;
  const int tid = threadIdx.x;

  if (bx < NBF) {
    const int sub = tid >> 9;    // batch group 0/1
    const int gtid = tid & 511;  // index within group (8 waves)
    float* sb = seq + (size_t)(bx * 2 + sub) * (Tn * Cn);
    const int l = tid & 63;
    const int w = gtid >> 6;         // wave-in-group 0..7
    const int c = l & 15;            // cp-chunk lane (reduction index)
    const int g = l >> 4;            // cc-group within wave
    const int ccb = w * 32 + g * 8;  // 8 consecutive cc
    const int cpb = c * 16;          // 16 consecutive cp
    // trans fragment: rows cpb+k, cc cols [ccb,ccb+4) and [ccb+4,ccb+8).
    float4 ta[16], tb[16];
#pragma unroll
    for (int k = 0; k < 16; ++k) {
      const float* tr = trans + (size_t)(cpb + k) * Cn + ccb;
      ta[k] = *(const float4*)(tr);
      tb[k] = *(const float4*)(tr + 4);
    }

    float* ab0 = &ab[sub][0][0];
    float* ab1 = &ab[sub][1][0];
    if (gtid < 64) *(float4*)(ab0 + apad(gtid)) = ((const float4*)sb)[gtid];
    const bool leader = (c == 0);
    // leader (w,g) owns cc [32w+8g,+8) = chunks 8w+2g, +1 (contiguous in
    // apad space since (8w+2g)&3 is 0 or 2).
    const int woff = apad(8 * w + 2 * g);
    float4 eL, eH, pnaL, pnaH;
    if (leader) {
      eL = *(const float4*)(sb + Cn + ccb);      // emissions[1] low half
      eH = *(const float4*)(sb + Cn + ccb + 4);  // emissions[1] high half
    }
    __syncthreads();

    for (int t = 1; t < Tn; ++t) {
      // 1) issue this step's alpha LDS reads immediately after the barrier
      const float* av = (t & 1) ? ab0 : ab1;
      float* aw = (t & 1) ? ab1 : ab0;
      const float* avc = av + c * 20;
      const float4 A0 = *(const float4*)(avc + 0);
      const float4 A1 = *(const float4*)(avc + 4);
      const float4 A2 = *(const float4*)(avc + 8);
      const float4 A3 = *(const float4*)(avc + 12);
      // 2) leader global traffic: lane-private; stays in flight across the
      //    relaxed barrier (pf consumed only next step -> latency hidden)
      float4 pfL, pfH;
      if (leader) {
        if (t > 1) {
          *(float4*)(sb + (size_t)(t - 1) * Cn + ccb) = pnaL;
          *(float4*)(sb + (size_t)(t - 1) * Cn + ccb + 4) = pnaH;
        }
        const int tn = (t + 1 < Tn) ? (t + 1) : (Tn - 1);
        pfL = *(const float4*)(sb + (size_t)tn * Cn + ccb);
        pfH = *(const float4*)(sb + (size_t)tn * Cn + ccb + 4);
      }
      // 3) MACs: 128 cells/lane, 8 independent fused-max3 chains
      float m0, m1, m2, m3, m4, m5, m6, m7;
      REDUCE_CC(m0, ta, x)
      REDUCE_CC(m1, ta, y)
      REDUCE_CC(m2, ta, z)
      REDUCE_CC(m3, ta, w)
      REDUCE_CC(m4, tb, x)
      REDUCE_CC(m5, tb, y)
      REDUCE_CC(m6, tb, z)
      REDUCE_CC(m7, tb, w)
      // rotate-reduce max across the 16 c-lanes of this DPP row (exact)
      DPP_STAGE8(0x128)
      DPP_STAGE8(0x124)
      DPP_STAGE8(0x122)
      DPP_STAGE8(0x121)
      if (leader) {
        float4 naL, naH;
        naL.x = m0 + eL.x; naL.y = m1 + eL.y; naL.z = m2 + eL.z; naL.w = m3 + eL.w;
        naH.x = m4 + eH.x; naH.y = m5 + eH.y; naH.z = m6 + eH.z; naH.w = m7 + eH.w;
        *(float4*)(aw + woff) = naL;
        *(float4*)(aw + woff + 4) = naH;
        pnaL = naL; pnaH = naH;
        eL = pfL; eH = pfH;
      }
      BAR_LGKM();  // LDS-ordered only; global ops remain outstanding
    }
    if (leader) {
      *(float4*)(sb + (size_t)(Tn - 1) * Cn + ccb) = pnaL;
      *(float4*)(sb + (size_t)(Tn - 1) * Cn + ccb + 4) = pnaH;
    }
  } else if (useT) {
    // 64x64-tile transpose of trans into transT, LDS-staged, +1-padded
    const int idx = bx - NBF;  // 0..15
    const int ti = idx >> 2, tj = idx & 3;
    const int tx = tid & 63, ty = tid >> 6;  // ty 0..15
#pragma unroll
    for (int q = 0; q < 4; ++q) {
      const int row = q * 16 + ty;
      lds[tx * 65 + row] = trans[(size_t)(ti * 64 + row) * Cn + tj * 64 + tx];
    }
    __syncthreads();
#pragma unroll
    for (int q = 0; q < 4; ++q) {
      const int row = q * 16 + ty;
      transT[(size_t)(tj * 64 + row) * Cn + ti * 64 + tx] = lds[row * 65 + tx];
    }
  }
}

// ---------------- bwd helpers ----------------
__device__ __forceinline__ float4 onehot4(int tg, int cp0) {
  float4 z;
  z.x = (tg == cp0 + 0) ? 1.0f : 0.0f; z.y = (tg == cp0 + 1) ? 1.0f : 0.0f;
  z.z = (tg == cp0 + 2) ? 1.0f : 0.0f; z.w = (tg == cp0 + 3) ? 1.0f : 0.0f;
  return z;
}

// Chain chunk: per step, the dependent row load hits the LDS transT cache for
// tag < TCROWS (~40cy) else L2 (~200cy). tag is SGPR-uniform -> scalar branch.
template<int K>
__device__ __forceinline__ int chain_chunk(
    const float* __restrict__ A, int* __restrict__ tags,
    const float* __restrict__ transT, const float* __restrict__ tc,
    int tag, int l) {
  const int cp0 = l * 4;
#pragma unroll
  for (int k = 0; k < K; ++k) {
    float4 tv;
    if (tag < TCROWS) {
      tv = *(const float4*)(tc + tag * Cn + cp0);
    } else {
      tv = *(const float4*)(transT + (size_t)tag * Cn + cp0);
    }
    const float4 ac = *(const float4*)(A + k * Cn + cp0);
    float v = ac.x + tv.x; int i = cp0;
    float vv; bool cnd;
    vv = ac.y + tv.y; cnd = vv > v; v = cnd ? vv : v; i = cnd ? cp0 + 1 : i;
    vv = ac.z + tv.z; cnd = vv > v; v = cnd ? vv : v; i = cnd ? cp0 + 2 : i;
    vv = ac.w + tv.w; cnd = vv > v; v = cnd ? vv : v; i = cnd ? cp0 + 3 : i;
    tag = argmax64_fast(v, i);
    if (l == 0) tags[k] = tag;
  }
  return tag;
}

// ---------------- Kernel B: producer-consumer backtrack + one-hot -------------
// Wave0: dependent chain. Waves1-2: alpha global->LDS ring (non-temporal).
// Wave3: one-hot stores (non-temporal). R10: 127 transT rows cached in LDS.
__global__ __launch_bounds__(256) void crf_bwd_kernel(
    const float* __restrict__ seq, const float* __restrict__ trans,
    const float* __restrict__ transT, float* __restrict__ out, int useT) {
  __shared__ float aL[2][16][Cn];     // 32 KB alpha ring
  __shared__ float tc[TCROWS * Cn];   // 127 KB transT row cache
  __shared__ int tagL[2][16];
  const int b = blockIdx.x;
  const int tid = threadIdx.x;
  const int wv = tid >> 6;
  const int l = tid & 63;
  const int cp0 = l * 4;
  const float* sb = seq + (size_t)b * (Tn * Cn);  // alpha trail
  float* ob = out + (size_t)b * (Tn * Cn);

  if (!useT) {
    if (wv == 0) {
      float4 a = *(const float4*)(sb + (size_t)(Tn - 1) * Cn + cp0);
      float v = a.x; int i = cp0; bool cnd;
      cnd = a.y > v; v = cnd ? a.y : v; i = cnd ? cp0 + 1 : i;
      cnd = a.z > v; v = cnd ? a.z : v; i = cnd ? cp0 + 2 : i;
      cnd = a.w > v; v = cnd ? a.w : v; i = cnd ? cp0 + 3 : i;
      int tag = argmax64_fast(v, i);
      *(float4*)(ob + (size_t)(Tn - 1) * Cn + cp0) = onehot4(tag, cp0);
      for (int t = Tn - 2; t >= 0; --t) {
        const float4 ac = *(const float4*)(sb + (size_t)t * Cn + cp0);
        float4 tv;
        tv.x = trans[(size_t)(cp0 + 0) * Cn + tag];
        tv.y = trans[(size_t)(cp0 + 1) * Cn + tag];
        tv.z = trans[(size_t)(cp0 + 2) * Cn + tag];
        tv.w = trans[(size_t)(cp0 + 3) * Cn + tag];
        float v2 = ac.x + tv.x; int i2 = cp0; float vv; bool c2;
        vv = ac.y + tv.y; c2 = vv > v2; v2 = c2 ? vv : v2; i2 = c2 ? cp0 + 1 : i2;
        vv = ac.z + tv.z; c2 = vv > v2; v2 = c2 ? vv : v2; i2 = c2 ? cp0 + 2 : i2;
        vv = ac.w + tv.w; c2 = vv > v2; v2 = c2 ? vv : v2; i2 = c2 ? cp0 + 3 : i2;
        tag = argmax64_fast(v2, i2);
        *(float4*)(ob + (size_t)t * Cn + cp0) = onehot4(tag, cp0);
      }
    }
    return;
  }

  // Preload the transT LDS cache: wave wv loads rows [32*wv, min(127, 32*wv+32))
  {
    const int r0 = wv * 32;
    const int r1 = (r0 + 32 < TCROWS) ? (r0 + 32) : TCROWS;
    for (int r = r0; r < r1; ++r)
      *(float4*)(&tc[r * Cn + cp0]) = *(const float4*)(transT + (size_t)r * Cn + cp0);
  }

  int tag = 0;
  if (wv == 0) {
    float4 a = *(const float4*)(sb + (size_t)(Tn - 1) * Cn + cp0);
    float v = a.x; int i = cp0; bool cnd;
    cnd = a.y > v; v = cnd ? a.y : v; i = cnd ? cp0 + 1 : i;
    cnd = a.z > v; v = cnd ? a.z : v; i = cnd ? cp0 + 2 : i;
    cnd = a.w > v; v = cnd ? a.w : v; i = cnd ? cp0 + 3 : i;
    tag = argmax64_fast(v, i);
    *(float4*)(ob + (size_t)(Tn - 1) * Cn + cp0) = onehot4(tag, cp0);
  } else if (wv <= 2) {
    const int s0 = (wv == 1) ? 0 : 8, s1 = (wv == 1) ? 8 : 15;
    for (int s = s0; s < s1; ++s)
      *(float4*)(&aL[0][s][cp0]) = nt_load4(sb + (size_t)(1022 - s) * Cn + cp0);
  }
  __syncthreads();

  int p = 0, t0 = 1022, K = 15, pt0 = 0, pK = 0;
  for (int ch = 0; ch < 64; ++ch) {
    const int nt0 = t0 - K;
    if (wv == 0) {
      if (ch == 0) tag = chain_chunk<15>(&aL[p][0][0], tagL[p], transT, tc, tag, l);
      else        tag = chain_chunk<16>(&aL[p][0][0], tagL[p], transT, tc, tag, l);
    } else if (wv <= 2) {
      if (ch < 63) {
        const int s0 = (wv == 1) ? 0 : 8, s1 = (wv == 1) ? 8 : 16;
        for (int s = s0; s < s1; ++s)
          *(float4*)(&aL[1 - p][s][cp0]) = nt_load4(sb + (size_t)(nt0 - s) * Cn + cp0);
      }
    } else {
      if (ch > 0) {
        for (int k = 0; k < pK; ++k)
          nt_store4(ob + (size_t)(pt0 - k) * Cn + cp0, onehot4(tagL[1 - p][k], cp0));
      }
    }
    __syncthreads();
    pt0 = t0; pK = K; t0 = nt0; K = 16; p ^= 1;
  }
  if (wv == 3) {
    for (int k = 0; k < 16; ++k)
      nt_store4(ob + (size_t)(15 - k) * Cn + cp0, onehot4(tagL[1][k], cp0));
  }
}

extern "C" void kernel_launch(void* const* d_in, const int* in_sizes, int n_in,
                              void* d_out, int out_size, void* d_ws, size_t ws_size,
                              hipStream_t stream) {
  float* seq = (float*)d_in[0];
  const float* trans = (const float*)d_in[1];
  float* out = (float*)d_out;
  float* transT = (float*)d_ws;
  const int useT = (ws_size >= (size_t)Cn * Cn * sizeof(float)) ? 1 : 0;

  crf_fwd_kernel<<<dim3(NBF + 16), dim3(1024), 0, stream>>>(seq, trans, transT, useT);
  crf_bwd_kernel<<<dim3(Bn), dim3(256), 0, stream>>>(seq, trans, transT, out, useT);
}

// Round 10
// 1220.518 us; speedup vs baseline: 7.9269x; 7.9269x over previous
//
#include <hip/hip_runtime.h>

#define Bn 64
#define Tn 1024
#define Cn 256
#define TCROWS 127  // transT rows cached in bwd LDS (127KB + 32KB ring + tags < 160KB)

// Native clang vector for nontemporal builtins (HIP float4 is a class type).
typedef float nv4 __attribute__((ext_vector_type(4)));
__device__ __forceinline__ float4 nt_load4(const float* p) {
  nv4 r = __builtin_nontemporal_load((const nv4*)p);
  return make_float4(r.x, r.y, r.z, r.w);
}
__device__ __forceinline__ void nt_store4(float* p, float4 v) {
  nv4 r = {v.x, v.y, v.z, v.w};
  __builtin_nontemporal_store(r, (nv4*)p);
}

// R12: barrier that waits ONLY on LDS (lgkmcnt), leaving lane-private global
// stores/loads in flight across the barrier (no cross-wave ordering needed).
#define BAR_LGKM() asm volatile("s_waitcnt lgkmcnt(0)\n\ts_barrier" ::: "memory")

// ---------------- DPP helpers ----------------
template<int CTRL>
__device__ __forceinline__ float dpp_mov_f(float x) {
  return __int_as_float(__builtin_amdgcn_update_dpp(0, __float_as_int(x), CTRL, 0xF, 0xF, true));
}

// R16 (verified -30us): packed (value,index) DPP argmax — no SALU round trips
// inside the backtrack chain. Tie-break = jnp.argmax (min index): in-lane
// strict '>' keeps earliest; cross-lane 'pv >= mv' lets the LOWER lane win
// (lane order == class order; shr1/2/4/8 prefix + bcast15 + bcast31 covers
// all 64 lanes — lane 63 holds the global winner). Untargeted lanes receive
// old = -inf, which never beats finite data.
template<int CTRL>
__device__ __forceinline__ void am_stage(float& mv, int& mi) {
  const float pv = __int_as_float(__builtin_amdgcn_update_dpp(
      (int)0xFF800000, __float_as_int(mv), CTRL, 0xF, 0xF, false));
  const int pi = __builtin_amdgcn_update_dpp(0, mi, CTRL, 0xF, 0xF, false);
  const bool take = (pv >= mv);
  mv = take ? pv : mv;
  mi = take ? pi : mi;
}
__device__ __forceinline__ int argmax64_fast(float v, int i) {
  float mv = v;
  int mi = i;
  am_stage<0x111>(mv, mi);  // row_shr:1
  am_stage<0x112>(mv, mi);  // row_shr:2
  am_stage<0x114>(mv, mi);  // row_shr:4
  am_stage<0x118>(mv, mi);  // row_shr:8
  am_stage<0x142>(mv, mi);  // row_bcast15
  am_stage<0x143>(mv, mi);  // row_bcast31 -> lane 63 has global argmax
  return __builtin_amdgcn_readlane(mi, 63);
}

// Padded alpha LDS layout (R3-verified: conflicts 5.0e7 -> 512):
// chunk m at float offset (m>>2)*20 + (m&3)*4. Buffer = 320 floats.
__device__ __forceinline__ int apad(int m) { return (m >> 2) * 20 + (m & 3) * 4; }

// Reduce 16 cp cells into accumulator M for one cc component CMP.
// Plain fmaxf chains: compiler fuses the pairs into v_max3_f32 (R11-verified
// null for explicit asm). Chain depth 8; exact (fp32 max is associative).
#define REDUCE_CC(M, CMP)                                                     \
  {                                                                           \
    M = fmaxf(a0.x + tr4[0].CMP, a0.y + tr4[1].CMP);                          \
    M = fmaxf(M, a0.z + tr4[2].CMP); M = fmaxf(M, a0.w + tr4[3].CMP);         \
    M = fmaxf(M, a1.x + tr4[4].CMP); M = fmaxf(M, a1.y + tr4[5].CMP);         \
    M = fmaxf(M, a1.z + tr4[6].CMP); M = fmaxf(M, a1.w + tr4[7].CMP);         \
    M = fmaxf(M, a2.x + tr4[8].CMP); M = fmaxf(M, a2.y + tr4[9].CMP);         \
    M = fmaxf(M, a2.z + tr4[10].CMP); M = fmaxf(M, a2.w + tr4[11].CMP);       \
    M = fmaxf(M, a3.x + tr4[12].CMP); M = fmaxf(M, a3.y + tr4[13].CMP);       \
    M = fmaxf(M, a3.z + tr4[14].CMP); M = fmaxf(M, a3.w + tr4[15].CMP);       \
  }

// ---------------- Kernel A: forward max-plus scan (+ trans transpose) ----------------
// R12/R16 structure — the verified fwd optimum (~916-921us): read-first loop
// body, leader global prefetch in flight across the lgkm-only barrier,
// compiler-scheduled fmaxf chains, 16 waves, L=16, 64-float reg fragment.
// Six structural variants all regressed (R13 flags +39%, R14 pk_add +17%,
// R15 8-wave +45%, R17 JIT reads +25%, R19 2-batch/block +900% via VGPR
// spill): the ~950cy/step above the VALU-issue window is overlap slack the
// compiler/HW schedule already minimizes for this decomposition. NOTE:
// launch_bounds(1024,4) caps usable VGPRs ~128/thread — per-lane register
// fragments must stay <= 64 floats or they spill to scratch (R19 lesson).
__global__ __launch_bounds__(1024, 4) void crf_fwd_kernel(
    float* __restrict__ seq, const float* __restrict__ trans,
    float* __restrict__ transT, int useT) {
  __shared__ float lds[64 * 65];
  const int bi = blockIdx.x;
  const int tid = threadIdx.x;

  if (bi < Bn) {
    float* sb = seq + (size_t)bi * (Tn * Cn);
    const int l = tid & 63;
    const int w = tid >> 6;     // wave 0..15
    const int c = l & 15;       // cp-chunk lane (reduction index)
    const int g = l >> 4;       // cc-group within wave
    const int ccb = w * 16 + g * 4;  // 4 consecutive cc
    const int cpb = c * 16;          // 16 consecutive cp
    float4 tr4[16];  // trans fragment (64 floats -> fits the VGPR budget)
#pragma unroll
    for (int k = 0; k < 16; ++k)
      tr4[k] = *(const float4*)(trans + (size_t)(cpb + k) * Cn + ccb);

    float* ab0 = lds;        // 320 floats (padded)
    float* ab1 = lds + 320;
    if (tid < 64) *(float4*)(ab0 + apad(tid)) = ((const float4*)sb)[tid];
    const bool leader = (c == 0);
    const int woff = apad(w * 4 + g);
    float4 e4, pna;
    if (leader) e4 = *(const float4*)(sb + Cn + ccb);  // emissions[1]
    __syncthreads();

    for (int t = 1; t < Tn; ++t) {
      // 1) issue this step's alpha LDS reads immediately after the barrier
      const float* av = (t & 1) ? ab0 : ab1;
      float* aw = (t & 1) ? ab1 : ab0;
      const float* avc = av + c * 20;
      const float4 a0 = *(const float4*)(avc + 0);
      const float4 a1 = *(const float4*)(avc + 4);
      const float4 a2 = *(const float4*)(avc + 8);
      const float4 a3 = *(const float4*)(avc + 12);
      // 2) leader global traffic: lane-private; stays in flight across the
      //    relaxed barrier (pf consumed only next step -> latency hidden)
      float4 pf;
      if (leader) {
        if (t > 1) *(float4*)(sb + (size_t)(t - 1) * Cn + ccb) = pna;
        const int tn = (t + 1 < Tn) ? (t + 1) : (Tn - 1);
        pf = *(const float4*)(sb + (size_t)tn * Cn + ccb);
      }
      // 3) MACs: 4 independent 8-deep chains (compiler fuses to v_max3)
      float m0, m1, m2, m3;
      REDUCE_CC(m0, x)
      REDUCE_CC(m1, y)
      REDUCE_CC(m2, z)
      REDUCE_CC(m3, w)
      // rotate-reduce max across the 16 c-lanes of this DPP row (exact)
      m0 = fmaxf(m0, dpp_mov_f<0x128>(m0)); m1 = fmaxf(m1, dpp_mov_f<0x128>(m1));
      m2 = fmaxf(m2, dpp_mov_f<0x128>(m2)); m3 = fmaxf(m3, dpp_mov_f<0x128>(m3));
      m0 = fmaxf(m0, dpp_mov_f<0x124>(m0)); m1 = fmaxf(m1, dpp_mov_f<0x124>(m1));
      m2 = fmaxf(m2, dpp_mov_f<0x124>(m2)); m3 = fmaxf(m3, dpp_mov_f<0x124>(m3));
      m0 = fmaxf(m0, dpp_mov_f<0x122>(m0)); m1 = fmaxf(m1, dpp_mov_f<0x122>(m1));
      m2 = fmaxf(m2, dpp_mov_f<0x122>(m2)); m3 = fmaxf(m3, dpp_mov_f<0x122>(m3));
      m0 = fmaxf(m0, dpp_mov_f<0x121>(m0)); m1 = fmaxf(m1, dpp_mov_f<0x121>(m1));
      m2 = fmaxf(m2, dpp_mov_f<0x121>(m2)); m3 = fmaxf(m3, dpp_mov_f<0x121>(m3));
      if (leader) {
        float4 na;
        na.x = m0 + e4.x; na.y = m1 + e4.y; na.z = m2 + e4.z; na.w = m3 + e4.w;
        *(float4*)(aw + woff) = na;
        pna = na;
        e4 = pf;
      }
      BAR_LGKM();  // LDS-ordered only; global ops remain outstanding
    }
    if (leader) *(float4*)(sb + (size_t)(Tn - 1) * Cn + ccb) = pna;
  } else if (useT) {
    // 64x64-tile transpose of trans into transT, LDS-staged, +1-padded
    const int idx = bi - Bn;  // 0..15
    const int ti = idx >> 2, tj = idx & 3;
    const int tx = tid & 63, ty = tid >> 6;  // ty 0..15
#pragma unroll
    for (int q = 0; q < 4; ++q) {
      const int row = q * 16 + ty;
      lds[tx * 65 + row] = trans[(size_t)(ti * 64 + row) * Cn + tj * 64 + tx];
    }
    __syncthreads();
#pragma unroll
    for (int q = 0; q < 4; ++q) {
      const int row = q * 16 + ty;
      transT[(size_t)(tj * 64 + row) * Cn + ti * 64 + tx] = lds[row * 65 + tx];
    }
  }
}

// ---------------- bwd helpers ----------------
__device__ __forceinline__ float4 onehot4(int tg, int cp0) {
  float4 z;
  z.x = (tg == cp0 + 0) ? 1.0f : 0.0f; z.y = (tg == cp0 + 1) ? 1.0f : 0.0f;
  z.z = (tg == cp0 + 2) ? 1.0f : 0.0f; z.w = (tg == cp0 + 3) ? 1.0f : 0.0f;
  return z;
}

// Chain chunk: per step, the dependent row load hits the LDS transT cache for
// tag < TCROWS (~40cy) else L2 (~200cy). tag is SGPR-uniform -> scalar branch.
template<int K>
__device__ __forceinline__ int chain_chunk(
    const float* __restrict__ A, int* __restrict__ tags,
    const float* __restrict__ transT, const float* __restrict__ tc,
    int tag, int l) {
  const int cp0 = l * 4;
#pragma unroll
  for (int k = 0; k < K; ++k) {
    float4 tv;
    if (tag < TCROWS) {
      tv = *(const float4*)(tc + tag * Cn + cp0);
    } else {
      tv = *(const float4*)(transT + (size_t)tag * Cn + cp0);
    }
    const float4 ac = *(const float4*)(A + k * Cn + cp0);
    float v = ac.x + tv.x; int i = cp0;
    float vv; bool cnd;
    vv = ac.y + tv.y; cnd = vv > v; v = cnd ? vv : v; i = cnd ? cp0 + 1 : i;
    vv = ac.z + tv.z; cnd = vv > v; v = cnd ? vv : v; i = cnd ? cp0 + 2 : i;
    vv = ac.w + tv.w; cnd = vv > v; v = cnd ? vv : v; i = cnd ? cp0 + 3 : i;
    tag = argmax64_fast(v, i);
    if (l == 0) tags[k] = tag;
  }
  return tag;
}

// ---------------- Kernel B: producer-consumer backtrack + one-hot -------------
// Wave0: dependent chain. Waves1-2: alpha global->LDS ring (non-temporal).
// Wave3: one-hot stores (non-temporal). R10: 127 transT rows cached in LDS.
__global__ __launch_bounds__(256) void crf_bwd_kernel(
    const float* __restrict__ seq, const float* __restrict__ trans,
    const float* __restrict__ transT, float* __restrict__ out, int useT) {
  __shared__ float aL[2][16][Cn];     // 32 KB alpha ring
  __shared__ float tc[TCROWS * Cn];   // 127 KB transT row cache
  __shared__ int tagL[2][16];
  const int b = blockIdx.x;
  const int tid = threadIdx.x;
  const int wv = tid >> 6;
  const int l = tid & 63;
  const int cp0 = l * 4;
  const float* sb = seq + (size_t)b * (Tn * Cn);  // alpha trail
  float* ob = out + (size_t)b * (Tn * Cn);

  if (!useT) {
    if (wv == 0) {
      float4 a = *(const float4*)(sb + (size_t)(Tn - 1) * Cn + cp0);
      float v = a.x; int i = cp0; bool cnd;
      cnd = a.y > v; v = cnd ? a.y : v; i = cnd ? cp0 + 1 : i;
      cnd = a.z > v; v = cnd ? a.z : v; i = cnd ? cp0 + 2 : i;
      cnd = a.w > v; v = cnd ? a.w : v; i = cnd ? cp0 + 3 : i;
      int tag = argmax64_fast(v, i);
      *(float4*)(ob + (size_t)(Tn - 1) * Cn + cp0) = onehot4(tag, cp0);
      for (int t = Tn - 2; t >= 0; --t) {
        const float4 ac = *(const float4*)(sb + (size_t)t * Cn + cp0);
        float4 tv;
        tv.x = trans[(size_t)(cp0 + 0) * Cn + tag];
        tv.y = trans[(size_t)(cp0 + 1) * Cn + tag];
        tv.z = trans[(size_t)(cp0 + 2) * Cn + tag];
        tv.w = trans[(size_t)(cp0 + 3) * Cn + tag];
        float v2 = ac.x + tv.x; int i2 = cp0; float vv; bool c2;
        vv = ac.y + tv.y; c2 = vv > v2; v2 = c2 ? vv : v2; i2 = c2 ? cp0 + 1 : i2;
        vv = ac.z + tv.z; c2 = vv > v2; v2 = c2 ? vv : v2; i2 = c2 ? cp0 + 2 : i2;
        vv = ac.w + tv.w; c2 = vv > v2; v2 = c2 ? vv : v2; i2 = c2 ? cp0 + 3 : i2;
        tag = argmax64_fast(v2, i2);
        *(float4*)(ob + (size_t)t * Cn + cp0) = onehot4(tag, cp0);
      }
    }
    return;
  }

  // Preload the transT LDS cache: wave wv loads rows [32*wv, min(127, 32*wv+32))
  {
    const int r0 = wv * 32;
    const int r1 = (r0 + 32 < TCROWS) ? (r0 + 32) : TCROWS;
    for (int r = r0; r < r1; ++r)
      *(float4*)(&tc[r * Cn + cp0]) = *(const float4*)(transT + (size_t)r * Cn + cp0);
  }

  int tag = 0;
  if (wv == 0) {
    float4 a = *(const float4*)(sb + (size_t)(Tn - 1) * Cn + cp0);
    float v = a.x; int i = cp0; bool cnd;
    cnd = a.y > v; v = cnd ? a.y : v; i = cnd ? cp0 + 1 : i;
    cnd = a.z > v; v = cnd ? a.z : v; i = cnd ? cp0 + 2 : i;
    cnd = a.w > v; v = cnd ? a.w : v; i = cnd ? cp0 + 3 : i;
    tag = argmax64_fast(v, i);
    *(float4*)(ob + (size_t)(Tn - 1) * Cn + cp0) = onehot4(tag, cp0);
  } else if (wv <= 2) {
    const int s0 = (wv == 1) ? 0 : 8, s1 = (wv == 1) ? 8 : 15;
    for (int s = s0; s < s1; ++s)
      *(float4*)(&aL[0][s][cp0]) = nt_load4(sb + (size_t)(1022 - s) * Cn + cp0);
  }
  __syncthreads();

  int p = 0, t0 = 1022, K = 15, pt0 = 0, pK = 0;
  for (int ch = 0; ch < 64; ++ch) {
    const int nt0 = t0 - K;
    if (wv == 0) {
      if (ch == 0) tag = chain_chunk<15>(&aL[p][0][0], tagL[p], transT, tc, tag, l);
      else        tag = chain_chunk<16>(&aL[p][0][0], tagL[p], transT, tc, tag, l);
    } else if (wv <= 2) {
      if (ch < 63) {
        const int s0 = (wv == 1) ? 0 : 8, s1 = (wv == 1) ? 8 : 16;
        for (int s = s0; s < s1; ++s)
          *(float4*)(&aL[1 - p][s][cp0]) = nt_load4(sb + (size_t)(nt0 - s) * Cn + cp0);
      }
    } else {
      if (ch > 0) {
        for (int k = 0; k < pK; ++k)
          nt_store4(ob + (size_t)(pt0 - k) * Cn + cp0, onehot4(tagL[1 - p][k], cp0));
      }
    }
    __syncthreads();
    pt0 = t0; pK = K; t0 = nt0; K = 16; p ^= 1;
  }
  if (wv == 3) {
    for (int k = 0; k < 16; ++k)
      nt_store4(ob + (size_t)(15 - k) * Cn + cp0, onehot4(tagL[1][k], cp0));
  }
}

extern "C" void kernel_launch(void* const* d_in, const int* in_sizes, int n_in,
                              void* d_out, int out_size, void* d_ws, size_t ws_size,
                              hipStream_t stream) {
  float* seq = (float*)d_in[0];
  const float* trans = (const float*)d_in[1];
  float* out = (float*)d_out;
  float* transT = (float*)d_ws;
  const int useT = (ws_size >= (size_t)Cn * Cn * sizeof(float)) ? 1 : 0;

  crf_fwd_kernel<<<dim3(Bn + 16), dim3(1024), 0, stream>>>(seq, trans, transT, useT);
  crf_bwd_kernel<<<dim3(Bn), dim3(256), 0, stream>>>(seq, trans, transT, out, useT);
}